// Round 3
// baseline (1105.467 us; speedup 1.0000x reference)
//
#include <hip/hip_runtime.h>

// MiniCPM-style decode step: L=8 B=4 H=16 HKV=8 D=64 S=2048 HID=1024 FF=2816
#define L_   8
#define B_   4
#define H_   16
#define HKV_ 8
#define D_   64
#define S_   2048
#define HID_ 1024
#define FF_  2816
#define G_   2
#define NS_  8
#define CH_  (S_ / NS_)          // 256 positions per attention split
#define EPS_ 1e-5f
#define MUP_ 0.49497474683058327f   // 1.4/sqrt(8)
#define SCALE_ 0.125f               // 1/sqrt(64)

// d_out is FLOAT32 (reference outputs are f32/int32): [h 4096 | k_upd 16384 | v_upd 16384 | pos+1]
#define OUT_H   0
#define OUT_K   4096
#define OUT_V   (4096 + 16384)
#define OUT_POS (4096 + 16384 + 16384)   // 36864

// ---------------- workspace layout (floats) ----------------
enum {
  WS_H    = 0,                    // 4096
  WS_Q    = WS_H + 4096,          // 4096
  WS_KN   = WS_Q + 4096,          // 2048
  WS_VN   = WS_KN + 2048,         // 2048
  WS_QKVP = WS_VN + 2048,         // 131072
  WS_AM   = WS_QKVP + 131072,     // 512
  WS_AL   = WS_AM + 512,          // 512
  WS_AO   = WS_AL + 512,          // 32768
  WS_O    = WS_AO + 32768,        // 4096
  WS_OP   = WS_O + 4096,          // 65536
  WS_GP   = WS_OP + 65536,        // 180224
  WS_UP   = WS_GP + 180224,       // 180224
  WS_MID  = WS_UP + 180224,       // 11264
  WS_DP   = WS_MID + 11264,       // 45056
  WS_END  = WS_DP + 45056         // ~2.65 MB
};

// robust position decode: int32 -> f32 reinterpret -> fallback
__device__ __forceinline__ int read_pos_dev(const int* p) {
  int v = p[0];
  if (v >= 0 && v < S_) return v;
  float f = __int_as_float(v);
  if (f >= 0.0f && f <= (float)(S_ - 1)) return (int)(f + 0.5f);
  return 1500;  // deterministic last resort
}

__device__ __forceinline__ float wave_sum(float v) {
  for (int m = 1; m < 64; m <<= 1) v += __shfl_xor(v, m);
  return v;
}
__device__ __forceinline__ float wave_max(float v) {
  for (int m = 1; m < 64; m <<= 1) v = fmaxf(v, __shfl_xor(v, m));
  return v;
}

__device__ __forceinline__ void load_h_and_rms(const float* h, float* hh,
                                               float* red, float* rs) {
  int t = threadIdx.x;
  float part[4] = {0.f, 0.f, 0.f, 0.f};
  for (int j = 0; j < 16; ++j) {
    int idx = t + j * 256;
    float v = h[idx];
    hh[idx] = v;
    part[j >> 2] += v * v;
  }
  int w = t >> 6, d = t & 63;
  for (int b = 0; b < 4; ++b) {
    float s = wave_sum(part[b]);
    if (d == 0) red[w * 4 + b] = s;
  }
  __syncthreads();
  for (int b = 0; b < 4; ++b) {
    float s = red[b] + red[4 + b] + red[8 + b] + red[12 + b];
    rs[b] = rsqrtf(s * (1.0f / HID_) + EPS_);
  }
}

// ---------------- K0: copy x -> ws.h, plus early scalar write ----------------
__global__ void k_copy_x(const float* __restrict__ x, const int* __restrict__ posp,
                         float* ws, float* out) {
  int i = blockIdx.x * 256 + threadIdx.x;   // grid 16 -> 4096
  ws[WS_H + i] = x[i];
  if (i == 0) out[OUT_POS] = (float)(read_pos_dev(posp) + 1);
}

// ---------------- K1: QKV split-K GEMV (norm1 fused) ----------------
__global__ void k_qkv_part(const float* __restrict__ Wq, const float* __restrict__ Wk,
                           const float* __restrict__ Wv, const float* __restrict__ n1,
                           float* ws, int l) {
  int cb = blockIdx.x & 7;
  int kc = blockIdx.x >> 3;
  int t = threadIdx.x;
  __shared__ float hh[4096];
  __shared__ float red[16];
  __shared__ float xs[B_][64];
  float rs[4];
  load_h_and_rms(ws + WS_H, hh, red, rs);
  __syncthreads();
  {
    int b = t >> 6, ii = t & 63;
    int i = kc * 64 + ii;
    xs[b][ii] = hh[b * HID_ + i] * rs[b] * n1[l * HID_ + i];
  }
  __syncthreads();
  int col = cb * 256 + t;       // 0..2047: [0,1024)=q [1024,1536)=k [1536,2048)=v
  const float* W; int wcol, stride;
  if (col < 1024)      { W = Wq + (size_t)l * HID_ * 1024; wcol = col;        stride = 1024; }
  else if (col < 1536) { W = Wk + (size_t)l * HID_ * 512;  wcol = col - 1024; stride = 512;  }
  else                 { W = Wv + (size_t)l * HID_ * 512;  wcol = col - 1536; stride = 512;  }
  const float* wp = W + (size_t)(kc * 64) * stride + wcol;
  float acc[4] = {0.f, 0.f, 0.f, 0.f};
  for (int ii = 0; ii < 64; ++ii) {
    float w = wp[(size_t)ii * stride];
    acc[0] += w * xs[0][ii]; acc[1] += w * xs[1][ii];
    acc[2] += w * xs[2][ii]; acc[3] += w * xs[3][ii];
  }
  float* p = ws + WS_QKVP + ((size_t)kc * 2048 + col) * 4;
  p[0] = acc[0]; p[1] = acc[1]; p[2] = acc[2]; p[3] = acc[3];
}

// ---------------- K2: combine partials + RoPE + emit k_upd/v_upd (f32) ----------------
__global__ void k_qkv_finish(const int* __restrict__ posp, float* ws,
                             float* out, int l) {
  int cb = blockIdx.x;
  int t = threadIdx.x;
  int b = t >> 6, dd = t & 63;
  int col = cb * 64 + dd;
  float s = 0.f;
  const float* p = ws + WS_QKVP;
  for (int kc = 0; kc < 16; ++kc) s += p[((size_t)kc * 2048 + col) * 4 + b];
  __shared__ float raw[B_][64];
  raw[b][dd] = s;
  __syncthreads();
  int pos = read_pos_dev(posp);
  if (blockIdx.x == 0 && t == 0)
    out[OUT_POS] = (float)(pos + 1);   // redundant scalar write
  if (col < 1536) {
    int idx = dd & 31;
    float inv = expf(-(float)idx * (1.0f / 32.0f) * logf(10000.0f));
    float ang = (float)pos * inv;
    float c = cosf(ang), sn = sinf(ang);
    float partner = raw[b][dd ^ 32];
    float rot = (dd < 32) ? -partner : partner;
    float v = s * c + rot * sn;
    if (col < 1024) {
      ws[WS_Q + b * HID_ + col] = v;
    } else {
      int kv = (col - 1024) >> 6;
      ws[WS_KN + (b * HKV_ + kv) * 64 + dd] = v;
      out[OUT_K + (((size_t)l * B_ + b) * HKV_ + kv) * 64 + dd] = v;
    }
  } else {
    int kv = (col - 1536) >> 6;
    ws[WS_VN + (b * HKV_ + kv) * 64 + dd] = s;
    out[OUT_V + (((size_t)l * B_ + b) * HKV_ + kv) * 64 + dd] = s;
  }
}

// ---------------- K3: flash-decode partial attention ----------------
__global__ void k_attn_part(const float* __restrict__ kcache, const float* __restrict__ vcache,
                            const int* __restrict__ posp, float* ws, int l) {
  int bi = blockIdx.x;
  int ns = bi & (NS_ - 1);
  int bh = bi >> 3;
  int b = bh >> 3, kv = bh & 7;
  int t = threadIdx.x;
  int w = t >> 6, d = t & 63;
  int pos = read_pos_dev(posp);
  __shared__ float sc0[CH_], sc1[CH_];
  __shared__ float red[8];
  __shared__ float oacc[2][4][64];
  float q0 = ws[WS_Q + b * HID_ + (kv * G_ + 0) * 64 + d];
  float q1 = ws[WS_Q + b * HID_ + (kv * G_ + 1) * 64 + d];
  const float* Kb = kcache + (((size_t)l * B_ + b) * HKV_ + kv) * S_ * 64;
  const float* Vb = vcache + (((size_t)l * B_ + b) * HKV_ + kv) * S_ * 64;
  const float* knew = ws + WS_KN + (b * HKV_ + kv) * 64;
  const float* vnew = ws + WS_VN + (b * HKV_ + kv) * 64;
  int s0 = ns * CH_;
  for (int s = s0 + w; s < s0 + CH_; s += 4) {
    float kval = (s == pos) ? knew[d] : Kb[(size_t)s * 64 + d];
    float p0 = wave_sum(kval * q0);
    float p1 = wave_sum(kval * q1);
    if (d == 0) {
      bool valid = (s <= pos);
      sc0[s - s0] = valid ? p0 * SCALE_ : -1e30f;
      sc1[s - s0] = valid ? p1 * SCALE_ : -1e30f;
    }
  }
  __syncthreads();
  float v0 = sc0[t], v1 = sc1[t];
  float m0 = wave_max(v0), m1 = wave_max(v1);
  if (d == 0) { red[w] = m0; red[4 + w] = m1; }
  __syncthreads();
  m0 = fmaxf(fmaxf(red[0], red[1]), fmaxf(red[2], red[3]));
  m1 = fmaxf(fmaxf(red[4], red[5]), fmaxf(red[6], red[7]));
  float e0 = expf(v0 - m0), e1 = expf(v1 - m1);
  __syncthreads();
  sc0[t] = e0; sc1[t] = e1;
  float se0 = wave_sum(e0), se1 = wave_sum(e1);
  __syncthreads();
  if (d == 0) { red[w] = se0; red[4 + w] = se1; }
  __syncthreads();
  float l0 = red[0] + red[1] + red[2] + red[3];
  float l1 = red[4] + red[5] + red[6] + red[7];
  if (t == 0) {
    int base = ((b * HKV_ + kv) * G_) * NS_ + ns;
    ws[WS_AM + base]       = m0;
    ws[WS_AM + base + NS_] = m1;
    ws[WS_AL + base]       = l0;
    ws[WS_AL + base + NS_] = l1;
  }
  float a0 = 0.f, a1 = 0.f;
  for (int s = s0 + w; s < s0 + CH_; s += 4) {
    float vv = (s == pos) ? vnew[d] : Vb[(size_t)s * 64 + d];
    a0 += sc0[s - s0] * vv;
    a1 += sc1[s - s0] * vv;
  }
  oacc[0][w][d] = a0; oacc[1][w][d] = a1;
  __syncthreads();
  if (w == 0) {
    float r0 = oacc[0][0][d] + oacc[0][1][d] + oacc[0][2][d] + oacc[0][3][d];
    float r1 = oacc[1][0][d] + oacc[1][1][d] + oacc[1][2][d] + oacc[1][3][d];
    int h0 = kv * G_;
    ws[WS_AO + (((size_t)(b * H_ + h0))     * NS_ + ns) * 64 + d] = r0;
    ws[WS_AO + (((size_t)(b * H_ + h0 + 1)) * NS_ + ns) * 64 + d] = r1;
  }
}

// ---------------- K4: combine flash partials ----------------
__global__ void k_attn_comb(float* ws) {
  int idx = blockIdx.x * 256 + threadIdx.x;
  int d = idx & 63, h = (idx >> 6) & 15, b = idx >> 10;
  int kv = h >> 1, gg = h & 1;
  int mb = ((b * HKV_ + kv) * G_ + gg) * NS_;
  float mx = -1e30f;
  for (int ns = 0; ns < NS_; ++ns) mx = fmaxf(mx, ws[WS_AM + mb + ns]);
  float lsum = 0.f, osum = 0.f;
  for (int ns = 0; ns < NS_; ++ns) {
    float wgt = expf(ws[WS_AM + mb + ns] - mx);
    lsum += wgt * ws[WS_AL + mb + ns];
    osum += wgt * ws[WS_AO + (((size_t)(b * H_ + h)) * NS_ + ns) * 64 + d];
  }
  ws[WS_O + b * HID_ + h * 64 + d] = osum / lsum;
}

// ---------------- K5: o-proj split-K GEMV ----------------
__global__ void k_oproj_part(const float* __restrict__ Wo, float* ws, int l) {
  int cb = blockIdx.x & 3, kc = blockIdx.x >> 2;
  int t = threadIdx.x;
  __shared__ float xs[B_][64];
  {
    int b = t >> 6, ii = t & 63;
    xs[b][ii] = ws[WS_O + b * HID_ + kc * 64 + ii];
  }
  __syncthreads();
  int col = cb * 256 + t;
  const float* wp = Wo + ((size_t)l * HID_ + kc * 64) * HID_ + col;
  float acc[4] = {0.f, 0.f, 0.f, 0.f};
  for (int ii = 0; ii < 64; ++ii) {
    float w = wp[(size_t)ii * HID_];
    acc[0] += w * xs[0][ii]; acc[1] += w * xs[1][ii];
    acc[2] += w * xs[2][ii]; acc[3] += w * xs[3][ii];
  }
  float* p = ws + WS_OP + ((size_t)kc * HID_ + col) * 4;
  p[0] = acc[0]; p[1] = acc[1]; p[2] = acc[2]; p[3] = acc[3];
}

__global__ void k_oproj_fin(float* ws) {
  int idx = blockIdx.x * 256 + threadIdx.x;
  int col = idx & 1023, b = idx >> 10;
  float s = 0.f;
  for (int kc = 0; kc < 16; ++kc) s += ws[WS_OP + ((size_t)kc * HID_ + col) * 4 + b];
  ws[WS_H + b * HID_ + col] += MUP_ * s;
}

// ---------------- K7: gate/up split-K GEMV (norm2 fused) ----------------
__global__ void k_gateup_part(const float* __restrict__ Wg, const float* __restrict__ Wu,
                              const float* __restrict__ n2, float* ws, int l) {
  int cb = blockIdx.x % 11, kc = blockIdx.x / 11;
  int t = threadIdx.x;
  __shared__ float hh[4096];
  __shared__ float red[16];
  __shared__ float xs[B_][64];
  float rs[4];
  load_h_and_rms(ws + WS_H, hh, red, rs);
  __syncthreads();
  {
    int b = t >> 6, ii = t & 63;
    int i = kc * 64 + ii;
    xs[b][ii] = hh[b * HID_ + i] * rs[b] * n2[l * HID_ + i];
  }
  __syncthreads();
  int col = cb * 256 + t;
  const float* wg = Wg + ((size_t)l * HID_ + kc * 64) * FF_ + col;
  const float* wu = Wu + ((size_t)l * HID_ + kc * 64) * FF_ + col;
  float ag[4] = {0.f,0.f,0.f,0.f}, au[4] = {0.f,0.f,0.f,0.f};
  for (int ii = 0; ii < 64; ++ii) {
    float g = wg[(size_t)ii * FF_], u = wu[(size_t)ii * FF_];
    ag[0] += g * xs[0][ii]; ag[1] += g * xs[1][ii];
    ag[2] += g * xs[2][ii]; ag[3] += g * xs[3][ii];
    au[0] += u * xs[0][ii]; au[1] += u * xs[1][ii];
    au[2] += u * xs[2][ii]; au[3] += u * xs[3][ii];
  }
  float* pg = ws + WS_GP + ((size_t)kc * FF_ + col) * 4;
  float* pu = ws + WS_UP + ((size_t)kc * FF_ + col) * 4;
  for (int b = 0; b < 4; ++b) { pg[b] = ag[b]; pu[b] = au[b]; }
}

__global__ void k_gateup_fin(float* ws) {
  int idx = blockIdx.x * 256 + threadIdx.x;
  int col = idx % FF_, b = idx / FF_;
  float g = 0.f, u = 0.f;
  for (int kc = 0; kc < 16; ++kc) {
    g += ws[WS_GP + ((size_t)kc * FF_ + col) * 4 + b];
    u += ws[WS_UP + ((size_t)kc * FF_ + col) * 4 + b];
  }
  float sig = 1.f / (1.f + expf(-g));
  ws[WS_MID + b * FF_ + col] = g * sig * u;
}

// ---------------- K9: down-proj split-K GEMV ----------------
__global__ void k_down_part(const float* __restrict__ Wd, float* ws, int l) {
  int cb = blockIdx.x & 3, kc = blockIdx.x >> 2;
  int t = threadIdx.x;
  __shared__ float xs[B_][256];
  for (int j = 0; j < 4; ++j) {
    int idx = t + j * 256;
    int b = idx >> 8, ii = idx & 255;
    xs[b][ii] = ws[WS_MID + b * FF_ + kc * 256 + ii];
  }
  __syncthreads();
  int col = cb * 256 + t;
  const float* wp = Wd + ((size_t)l * FF_ + kc * 256) * HID_ + col;
  float acc[4] = {0.f, 0.f, 0.f, 0.f};
  for (int ii = 0; ii < 256; ++ii) {
    float w = wp[(size_t)ii * HID_];
    acc[0] += w * xs[0][ii]; acc[1] += w * xs[1][ii];
    acc[2] += w * xs[2][ii]; acc[3] += w * xs[3][ii];
  }
  float* p = ws + WS_DP + ((size_t)kc * HID_ + col) * 4;
  p[0] = acc[0]; p[1] = acc[1]; p[2] = acc[2]; p[3] = acc[3];
}

__global__ void k_down_fin(float* ws) {
  int idx = blockIdx.x * 256 + threadIdx.x;
  int col = idx & 1023, b = idx >> 10;
  float s = 0.f;
  for (int kc = 0; kc < 11; ++kc) s += ws[WS_DP + ((size_t)kc * HID_ + col) * 4 + b];
  ws[WS_H + b * HID_ + col] += MUP_ * s;
}

// ---------------- K11: final RMSNorm -> f32 out ----------------
__global__ void k_final(const float* __restrict__ fw, const int* __restrict__ posp,
                        float* ws, float* out) {
  int b = blockIdx.x;
  int t = threadIdx.x;
  __shared__ float red[4];
  float vals[4];
  float part = 0.f;
  for (int j = 0; j < 4; ++j) {
    float v = ws[WS_H + b * HID_ + t + j * 256];
    vals[j] = v;
    part += v * v;
  }
  part = wave_sum(part);
  if ((t & 63) == 0) red[t >> 6] = part;
  __syncthreads();
  float ssum = red[0] + red[1] + red[2] + red[3];
  float rs = rsqrtf(ssum * (1.0f / HID_) + EPS_);
  for (int j = 0; j < 4; ++j) {
    int i = t + j * 256;
    out[OUT_H + b * HID_ + i] = vals[j] * rs * fw[i];
  }
  if (b == 0 && t == 0) out[OUT_POS] = (float)(read_pos_dev(posp) + 1);
}

// ---------------- K12: dedicated scalar writer (very last) ----------------
__global__ void k_scalar(const int* __restrict__ posp, float* out) {
  if (threadIdx.x == 0 && blockIdx.x == 0) {
    out[OUT_POS] = (float)(read_pos_dev(posp) + 1);
  }
}

extern "C" void kernel_launch(void* const* d_in, const int* in_sizes, int n_in,
                              void* d_out, int out_size, void* d_ws, size_t ws_size,
                              hipStream_t stream) {
  const float* x   = (const float*)d_in[0];
  const float* kc  = (const float*)d_in[1];
  const float* vc  = (const float*)d_in[2];
  const float* Wq  = (const float*)d_in[3];
  const float* Wk  = (const float*)d_in[4];
  const float* Wv  = (const float*)d_in[5];
  const float* Wo  = (const float*)d_in[6];
  const float* Wg  = (const float*)d_in[7];
  const float* Wu  = (const float*)d_in[8];
  const float* Wd  = (const float*)d_in[9];
  const float* n1  = (const float*)d_in[10];
  const float* n2  = (const float*)d_in[11];
  const float* fw  = (const float*)d_in[12];
  const int*   pos = (const int*)d_in[13];
  float* ws = (float*)d_ws;
  float* out = (float*)d_out;

  k_copy_x<<<16, 256, 0, stream>>>(x, pos, ws, out);

  for (int l = 0; l < L_; ++l) {
    k_qkv_part   <<<128, 256, 0, stream>>>(Wq, Wk, Wv, n1, ws, l);
    k_qkv_finish <<< 32, 256, 0, stream>>>(pos, ws, out, l);
    k_attn_part  <<<256, 256, 0, stream>>>(kc, vc, pos, ws, l);
    k_attn_comb  <<< 16, 256, 0, stream>>>(ws);
    k_oproj_part <<< 64, 256, 0, stream>>>(Wo, ws, l);
    k_oproj_fin  <<< 16, 256, 0, stream>>>(ws);
    k_gateup_part<<<176, 256, 0, stream>>>(Wg, Wu, n2, ws, l);
    k_gateup_fin <<< 44, 256, 0, stream>>>(ws);
    k_down_part  <<< 44, 256, 0, stream>>>(Wd, ws, l);
    k_down_fin   <<< 16, 256, 0, stream>>>(ws);
  }
  k_final<<<4, 256, 0, stream>>>(fw, pos, ws, out);
  k_scalar<<<1, 64, 0, stream>>>(pos, out);
}

// Round 4
// 565.671 us; speedup vs baseline: 1.9543x; 1.9543x over previous
//
#include <hip/hip_runtime.h>

// MiniCPM-style decode step: L=8 B=4 H=16 HKV=8 D=64 S=2048 HID=1024 FF=2816
#define L_   8
#define B_   4
#define H_   16
#define HKV_ 8
#define D_   64
#define S_   2048
#define HID_ 1024
#define FF_  2816
#define G_   2
#define NS_  8
#define CH_  (S_ / NS_)          // 256 positions per attention split
#define EPS_ 1e-5f
#define MUP_ 0.49497474683058327f   // 1.4/sqrt(8)
#define SCALE_ 0.125f               // 1/sqrt(64)

// d_out is FLOAT32: [h 4096 | k_upd 16384 | v_upd 16384 | pos+1]
#define OUT_H   0
#define OUT_K   4096
#define OUT_V   (4096 + 16384)
#define OUT_POS (4096 + 16384 + 16384)   // 36864

// ---------------- workspace layout (floats) ----------------
enum {
  WS_H    = 0,                     // 4096  h at layer entry
  WS_H2   = 4096,                  // 4096  h after attn residual
  WS_XN1  = 8192,                  // 4096  rms(h)*n1
  WS_XN2  = 12288,                 // 4096  rms(h2)*n2
  WS_QP   = 16384,                 // 32*2048*4 = 262144 qkv split-K partials
  WS_AM   = WS_QP + 262144,        // 512
  WS_AL   = WS_AM + 512,           // 512
  WS_AO   = WS_AL + 512,           // 32768
  WS_OP   = WS_AO + 32768,         // 32*1024*4 = 131072
  WS_GP   = WS_OP + 131072,        // 32*2816*4 = 360448
  WS_UP   = WS_GP + 360448,        // 360448
  WS_DP   = WS_UP + 360448,        // 44*1024*4 = 180224
  WS_END  = WS_DP + 180224         // ~5.4 MB
};

__device__ __forceinline__ int read_pos_dev(const int* p) {
  int v = p[0];
  if (v >= 0 && v < S_) return v;
  float f = __int_as_float(v);
  if (f >= 0.0f && f <= (float)(S_ - 1)) return (int)(f + 0.5f);
  return 1500;
}

__device__ __forceinline__ float wave_sum(float v) {
  for (int m = 1; m < 64; m <<= 1) v += __shfl_xor(v, m);
  return v;
}
__device__ __forceinline__ float wave_max(float v) {
  for (int m = 1; m < 64; m <<= 1) v = fmaxf(v, __shfl_xor(v, m));
  return v;
}

// ---------------- k_h1: h update (+final variant). grid 4 (one block per batch) ----
// mode 0: h = x (layer 0), write H + XN1(n1[l])
// mode 1: h = H2 + MUP*combine(DP), write H + XN1(n1[l])
// mode 2: h = H2 + MUP*combine(DP), write out = rms(h)*fw, plus pos+1
__global__ void k_h1(const float* __restrict__ x, const float* __restrict__ nw,
                     const int* __restrict__ posp, float* ws, float* out,
                     int l, int mode) {
  int b = blockIdx.x, t = threadIdx.x;
  float hv[4];
  float part = 0.f;
  for (int j = 0; j < 4; ++j) {
    int col = t + j * 256;
    float h;
    if (mode == 0) {
      h = x[b * HID_ + col];
    } else {
      float s = 0.f;
      #pragma unroll
      for (int kcd = 0; kcd < 44; ++kcd)
        s += ws[WS_DP + ((size_t)kcd * HID_ + col) * 4 + b];
      h = ws[WS_H2 + b * HID_ + col] + MUP_ * s;
    }
    hv[j] = h; part += h * h;
  }
  part = wave_sum(part);
  __shared__ float red[4];
  if ((t & 63) == 0) red[t >> 6] = part;
  __syncthreads();
  float ss = red[0] + red[1] + red[2] + red[3];
  float rs = rsqrtf(ss * (1.0f / HID_) + EPS_);
  for (int j = 0; j < 4; ++j) {
    int col = t + j * 256;
    if (mode == 2) {
      out[OUT_H + b * HID_ + col] = hv[j] * rs * nw[col];
    } else {
      ws[WS_H + b * HID_ + col] = hv[j];
      ws[WS_XN1 + b * HID_ + col] = hv[j] * rs * nw[l * HID_ + col];
    }
  }
  if (mode == 2 && b == 0 && t == 0)
    out[OUT_POS] = (float)(read_pos_dev(posp) + 1);
}

// ---------------- k_h2: h2 = H + MUP*combine(OP), write H2 + XN2. grid 4 ----------
__global__ void k_h2(const float* __restrict__ n2, float* ws, int l) {
  int b = blockIdx.x, t = threadIdx.x;
  float hv[4];
  float part = 0.f;
  for (int j = 0; j < 4; ++j) {
    int col = t + j * 256;
    float s = 0.f;
    #pragma unroll
    for (int kc = 0; kc < 32; ++kc)
      s += ws[WS_OP + ((size_t)kc * HID_ + col) * 4 + b];
    float h = ws[WS_H + b * HID_ + col] + MUP_ * s;
    hv[j] = h; part += h * h;
  }
  part = wave_sum(part);
  __shared__ float red[4];
  if ((t & 63) == 0) red[t >> 6] = part;
  __syncthreads();
  float ss = red[0] + red[1] + red[2] + red[3];
  float rs = rsqrtf(ss * (1.0f / HID_) + EPS_);
  for (int j = 0; j < 4; ++j) {
    int col = t + j * 256;
    ws[WS_H2 + b * HID_ + col] = hv[j];
    ws[WS_XN2 + b * HID_ + col] = hv[j] * rs * n2[l * HID_ + col];
  }
}

// ---------------- k_qkv: split-K GEMV partials. grid 256 (8 cb x 32 kc) ----------
__global__ void k_qkv(const float* __restrict__ Wq, const float* __restrict__ Wk,
                      const float* __restrict__ Wv, float* ws, int l) {
  int cb = blockIdx.x & 7, kc = blockIdx.x >> 3;
  int t = threadIdx.x;
  int col = cb * 256 + t;          // 0..2047: [0,1024)=q [1024,1536)=k [1536,2048)=v
  const float* W; int wcol, stride;
  if (col < 1024)      { W = Wq + (size_t)l * HID_ * 1024; wcol = col;        stride = 1024; }
  else if (col < 1536) { W = Wk + (size_t)l * HID_ * 512;  wcol = col - 1024; stride = 512;  }
  else                 { W = Wv + (size_t)l * HID_ * 512;  wcol = col - 1536; stride = 512;  }
  const float* wp = W + (size_t)(kc * 32) * stride + wcol;
  const float* __restrict__ xn = ws + WS_XN1 + kc * 32;   // wave-uniform reads
  float a0 = 0.f, a1 = 0.f, a2 = 0.f, a3 = 0.f;
  #pragma unroll
  for (int ii = 0; ii < 32; ++ii) {
    float w = wp[(size_t)ii * stride];
    a0 += w * xn[ii];
    a1 += w * xn[1024 + ii];
    a2 += w * xn[2048 + ii];
    a3 += w * xn[3072 + ii];
  }
  *(float4*)(ws + WS_QP + ((size_t)kc * 2048 + col) * 4) = make_float4(a0, a1, a2, a3);
}

// ---------------- k_attn: fused qkv-combine + rope + kv-out + flash chunk --------
// grid 256 = (b,kv) x ns; block 256 (4 waves)
__global__ void k_attn(const float* __restrict__ kcache, const float* __restrict__ vcache,
                       const int* __restrict__ posp, float* ws, float* out, int l) {
  int bi = blockIdx.x;
  int ns = bi & 7, bh = bi >> 3, b = bh >> 3, kv = bh & 7;
  int t = threadIdx.x;
  int w = t >> 6, lane = t & 63;
  int r = lane >> 4, c = lane & 15;
  int pos = read_pos_dev(posp);

  __shared__ __align__(16) float qL[2][64];
  __shared__ __align__(16) float knL[64], vnL[64];
  __shared__ float sc0[CH_], sc1[CH_], red[8], rawL[256];
  __shared__ __align__(16) float oacc[2][4][64];

  // Phase A: combine QKV partials for this (b,kv); rope q,k; stage; kv-out (ns==0)
  {
    int cg;
    if (t < 128)      cg = (kv * 2 + (t >> 6)) * 64 + (t & 63);
    else if (t < 192) cg = 1024 + kv * 64 + (t & 63);
    else              cg = 1536 + kv * 64 + (t & 63);
    float s = 0.f;
    #pragma unroll
    for (int kc = 0; kc < 32; ++kc)
      s += ws[WS_QP + ((size_t)kc * 2048 + cg) * 4 + b];
    rawL[t] = s;
  }
  __syncthreads();
  {
    int dd = t & 63;
    if (t < 192) {   // rope on q (t<128) and k (128..191)
      int idx = dd & 31;
      float inv = expf(-(float)idx * (1.0f / 32.0f) * 9.210340371976184f); // ln(1e4)
      float ang = (float)pos * inv;
      float sn, cs; sincosf(ang, &sn, &cs);
      float partner = rawL[t ^ 32];
      float rot = (dd < 32) ? -partner : partner;
      float v = rawL[t] * cs + rot * sn;
      if (t < 128) qL[t >> 6][dd] = v;
      else {
        knL[dd] = v;
        if (ns == 0) out[OUT_K + (((size_t)l * B_ + b) * HKV_ + kv) * 64 + dd] = v;
      }
    } else {
      vnL[dd] = rawL[t];
      if (ns == 0) out[OUT_V + (((size_t)l * B_ + b) * HKV_ + kv) * 64 + dd] = rawL[t];
    }
  }
  __syncthreads();

  const float* Kb = kcache + (((size_t)l * B_ + b) * HKV_ + kv) * S_ * 64;
  const float* Vb = vcache + (((size_t)l * B_ + b) * HKV_ + kv) * S_ * 64;
  int s0 = ns * CH_;
  float4 q0 = *(const float4*)&qL[0][4 * c];
  float4 q1 = *(const float4*)&qL[1][4 * c];

  // Phase B: scores. 4 rows per wave per iter (float4 per lane over 16 lanes)
  #pragma unroll
  for (int it = 0; it < 16; ++it) {
    int s = s0 + it * 16 + w * 4 + r;
    float d0 = 0.f, d1 = 0.f;
    bool valid = (s <= pos);
    if (valid) {
      float4 k4 = (s == pos) ? *(const float4*)&knL[4 * c]
                             : *(const float4*)&Kb[(size_t)s * 64 + 4 * c];
      d0 = k4.x * q0.x + k4.y * q0.y + k4.z * q0.z + k4.w * q0.w;
      d1 = k4.x * q1.x + k4.y * q1.y + k4.z * q1.z + k4.w * q1.w;
    }
    #pragma unroll
    for (int m = 1; m <= 8; m <<= 1) { d0 += __shfl_xor(d0, m); d1 += __shfl_xor(d1, m); }
    if (c == 0) {
      sc0[s - s0] = valid ? d0 * SCALE_ : -1e30f;
      sc1[s - s0] = valid ? d1 * SCALE_ : -1e30f;
    }
  }
  __syncthreads();

  // Phase C: softmax over the chunk
  float v0 = sc0[t], v1 = sc1[t];
  float m0 = wave_max(v0), m1 = wave_max(v1);
  if (lane == 0) { red[w] = m0; red[4 + w] = m1; }
  __syncthreads();
  m0 = fmaxf(fmaxf(red[0], red[1]), fmaxf(red[2], red[3]));
  m1 = fmaxf(fmaxf(red[4], red[5]), fmaxf(red[6], red[7]));
  float e0 = expf(v0 - m0), e1 = expf(v1 - m1);
  __syncthreads();
  sc0[t] = e0; sc1[t] = e1;
  float se0 = wave_sum(e0), se1 = wave_sum(e1);
  if (lane == 0) { red[w] = se0; red[4 + w] = se1; }
  __syncthreads();
  if (t == 0) {
    float l0 = red[0] + red[1] + red[2] + red[3];
    float l1 = red[4] + red[5] + red[6] + red[7];
    int base = ((b * HKV_ + kv) * G_) * NS_ + ns;
    ws[WS_AM + base]       = m0;
    ws[WS_AM + base + NS_] = m1;
    ws[WS_AL + base]       = l0;
    ws[WS_AL + base + NS_] = l1;
  }

  // Phase D: PV
  float4 a0 = make_float4(0.f, 0.f, 0.f, 0.f);
  float4 a1 = make_float4(0.f, 0.f, 0.f, 0.f);
  #pragma unroll
  for (int it = 0; it < 16; ++it) {
    int s = s0 + it * 16 + w * 4 + r;
    if (s <= pos) {
      float4 v4 = (s == pos) ? *(const float4*)&vnL[4 * c]
                             : *(const float4*)&Vb[(size_t)s * 64 + 4 * c];
      float p0 = sc0[s - s0], p1 = sc1[s - s0];
      a0.x += p0 * v4.x; a0.y += p0 * v4.y; a0.z += p0 * v4.z; a0.w += p0 * v4.w;
      a1.x += p1 * v4.x; a1.y += p1 * v4.y; a1.z += p1 * v4.z; a1.w += p1 * v4.w;
    }
  }
  #pragma unroll
  for (int m = 16; m <= 32; m <<= 1) {
    a0.x += __shfl_xor(a0.x, m); a0.y += __shfl_xor(a0.y, m);
    a0.z += __shfl_xor(a0.z, m); a0.w += __shfl_xor(a0.w, m);
    a1.x += __shfl_xor(a1.x, m); a1.y += __shfl_xor(a1.y, m);
    a1.z += __shfl_xor(a1.z, m); a1.w += __shfl_xor(a1.w, m);
  }
  if (r == 0) {
    *(float4*)&oacc[0][w][4 * c] = a0;
    *(float4*)&oacc[1][w][4 * c] = a1;
  }
  __syncthreads();
  if (w == 0) {   // t < 64
    float r0 = oacc[0][0][t] + oacc[0][1][t] + oacc[0][2][t] + oacc[0][3][t];
    float r1 = oacc[1][0][t] + oacc[1][1][t] + oacc[1][2][t] + oacc[1][3][t];
    int h0 = kv * 2;
    ws[WS_AO + (((size_t)(b * H_ + h0))     * NS_ + ns) * 64 + t] = r0;
    ws[WS_AO + (((size_t)(b * H_ + h0 + 1)) * NS_ + ns) * 64 + t] = r1;
  }
}

// ---------------- k_oproj: fused attn-combine + split-K GEMV. grid 128 (4cb x 32kc)
__global__ void k_oproj(const float* __restrict__ Wo, float* ws, int l) {
  int cb = blockIdx.x & 3, kc = blockIdx.x >> 2;
  int t = threadIdx.x;
  __shared__ __align__(16) float oT[32][4];   // [jj][b]
  if (t < 128) {
    int bb = t >> 5, jj = t & 31;
    int dim = kc * 32 + jj;
    int h = dim >> 6, d = dim & 63;
    int mb = ((bb * HKV_ + (h >> 1)) * G_ + (h & 1)) * NS_;
    float mx = -1e30f;
    #pragma unroll
    for (int n = 0; n < 8; ++n) mx = fmaxf(mx, ws[WS_AM + mb + n]);
    float ls = 0.f, os = 0.f;
    #pragma unroll
    for (int n = 0; n < 8; ++n) {
      float wg = expf(ws[WS_AM + mb + n] - mx);
      ls += wg * ws[WS_AL + mb + n];
      os += wg * ws[WS_AO + (((size_t)(bb * H_ + h)) * NS_ + n) * 64 + d];
    }
    oT[jj][bb] = os / ls;
  }
  __syncthreads();
  int col = cb * 256 + t;
  const float* wp = Wo + ((size_t)l * HID_ + kc * 32) * HID_ + col;
  float a0 = 0.f, a1 = 0.f, a2 = 0.f, a3 = 0.f;
  #pragma unroll
  for (int ii = 0; ii < 32; ++ii) {
    float w = wp[(size_t)ii * HID_];
    float4 o4 = *(const float4*)&oT[ii][0];
    a0 += w * o4.x; a1 += w * o4.y; a2 += w * o4.z; a3 += w * o4.w;
  }
  *(float4*)(ws + WS_OP + ((size_t)kc * HID_ + col) * 4) = make_float4(a0, a1, a2, a3);
}

// ---------------- k_gateup: split-K GEMV partials. grid 352 (11 cb x 32 kc) ------
__global__ void k_gateup(const float* __restrict__ Wg, const float* __restrict__ Wu,
                         float* ws, int l) {
  int cb = blockIdx.x % 11, kc = blockIdx.x / 11;
  int t = threadIdx.x;
  int col = cb * 256 + t;
  const float* wg = Wg + ((size_t)l * HID_ + kc * 32) * FF_ + col;
  const float* wu = Wu + ((size_t)l * HID_ + kc * 32) * FF_ + col;
  const float* __restrict__ xn = ws + WS_XN2 + kc * 32;
  float g0 = 0.f, g1 = 0.f, g2 = 0.f, g3 = 0.f;
  float u0 = 0.f, u1 = 0.f, u2 = 0.f, u3 = 0.f;
  #pragma unroll
  for (int ii = 0; ii < 32; ++ii) {
    float g = wg[(size_t)ii * FF_], u = wu[(size_t)ii * FF_];
    float x0 = xn[ii], x1 = xn[1024 + ii], x2 = xn[2048 + ii], x3 = xn[3072 + ii];
    g0 += g * x0; g1 += g * x1; g2 += g * x2; g3 += g * x3;
    u0 += u * x0; u1 += u * x1; u2 += u * x2; u3 += u * x3;
  }
  *(float4*)(ws + WS_GP + ((size_t)kc * FF_ + col) * 4) = make_float4(g0, g1, g2, g3);
  *(float4*)(ws + WS_UP + ((size_t)kc * FF_ + col) * 4) = make_float4(u0, u1, u2, u3);
}

// ---------------- k_down: fused silu-combine + split-K GEMV. grid 176 (4cb x 44kc)
__global__ void k_down(const float* __restrict__ Wd, float* ws, int l) {
  int cb = blockIdx.x & 3, kc = blockIdx.x >> 2;   // kc 0..43
  int t = threadIdx.x;
  __shared__ __align__(16) float mT[64][4];   // [jj][b]
  {
    int jj = t >> 2, bb = t & 3;
    int f = kc * 64 + jj;
    float g = 0.f, u = 0.f;
    #pragma unroll
    for (int k2 = 0; k2 < 32; ++k2) {
      g += ws[WS_GP + ((size_t)k2 * FF_ + f) * 4 + bb];
      u += ws[WS_UP + ((size_t)k2 * FF_ + f) * 4 + bb];
    }
    float sig = 1.f / (1.f + expf(-g));
    mT[jj][bb] = g * sig * u;
  }
  __syncthreads();
  int col = cb * 256 + t;
  const float* wp = Wd + ((size_t)l * FF_ + kc * 64) * HID_ + col;
  float a0 = 0.f, a1 = 0.f, a2 = 0.f, a3 = 0.f;
  #pragma unroll
  for (int ii = 0; ii < 64; ++ii) {
    float w = wp[(size_t)ii * HID_];
    float4 m4 = *(const float4*)&mT[ii][0];
    a0 += w * m4.x; a1 += w * m4.y; a2 += w * m4.z; a3 += w * m4.w;
  }
  *(float4*)(ws + WS_DP + ((size_t)kc * HID_ + col) * 4) = make_float4(a0, a1, a2, a3);
}

extern "C" void kernel_launch(void* const* d_in, const int* in_sizes, int n_in,
                              void* d_out, int out_size, void* d_ws, size_t ws_size,
                              hipStream_t stream) {
  const float* x   = (const float*)d_in[0];
  const float* kc  = (const float*)d_in[1];
  const float* vc  = (const float*)d_in[2];
  const float* Wq  = (const float*)d_in[3];
  const float* Wk  = (const float*)d_in[4];
  const float* Wv  = (const float*)d_in[5];
  const float* Wo  = (const float*)d_in[6];
  const float* Wg  = (const float*)d_in[7];
  const float* Wu  = (const float*)d_in[8];
  const float* Wd  = (const float*)d_in[9];
  const float* n1  = (const float*)d_in[10];
  const float* n2  = (const float*)d_in[11];
  const float* fw  = (const float*)d_in[12];
  const int*   pos = (const int*)d_in[13];
  float* ws  = (float*)d_ws;
  float* out = (float*)d_out;

  k_h1<<<4, 256, 0, stream>>>(x, n1, pos, ws, out, 0, 0);
  for (int l = 0; l < L_; ++l) {
    k_qkv   <<<256, 256, 0, stream>>>(Wq, Wk, Wv, ws, l);
    k_attn  <<<256, 256, 0, stream>>>(kc, vc, pos, ws, out, l);
    k_oproj <<<128, 256, 0, stream>>>(Wo, ws, l);
    k_h2    <<<  4, 256, 0, stream>>>(n2, ws, l);
    k_gateup<<<352, 256, 0, stream>>>(Wg, Wu, ws, l);
    k_down  <<<176, 256, 0, stream>>>(Wd, ws, l);
    if (l < L_ - 1) k_h1<<<4, 256, 0, stream>>>(x, n1, pos, ws, out, l + 1, 1);
  }
  k_h1<<<4, 256, 0, stream>>>(x, fw, pos, ws, out, 0, 2);
}